// Round 13
// baseline (499.627 us; speedup 1.0000x reference)
//
#include <hip/hip_runtime.h>
#include <hip/hip_bf16.h>
#include <cstdint>
#include <cstddef>

#define BS   4
#define NN   2048
#define NH   2
#define FIN  768
#define FOUT 768
#define NEG_SLOPE 0.2f

typedef __attribute__((ext_vector_type(8))) short short8;
typedef __attribute__((ext_vector_type(4))) float float4v;

static __device__ __forceinline__ float bits2f(unsigned short u) {
    union { unsigned int i; float f; } v; v.i = ((unsigned int)u) << 16; return v.f;
}
// RNE fp32 -> bf16 bits
static __device__ __forceinline__ unsigned short f2bits(float f) {
    union { float f; unsigned int i; } v; v.f = f;
    unsigned int x = v.i;
    unsigned int r = x + 0x7fffu + ((x >> 16) & 1u);
    return (unsigned short)(r >> 16);
}
// fast tanh via hardware exp; rel err ~1e-6
static __device__ __forceinline__ float fast_tanh(float x) {
    float xc = fminf(fmaxf(x, -20.f), 20.f);
    float e = __expf(2.f * xc);
    return (e - 1.f) / (e + 1.f);
}
// async global->LDS, 16B per lane; lds base wave-uniform, lane lands at +lane*16
static __device__ __forceinline__ void async_copy16(void* lds, const void* g) {
    __builtin_amdgcn_global_load_lds(
        (const __attribute__((address_space(1))) unsigned int*)g,
        (__attribute__((address_space(3))) unsigned int*)lds, 16, 0, 0);
}

// Per-block dtype detection (wave ballot; uniform result)
static __device__ __forceinline__ bool detect_isf32(const unsigned short* h_raw) {
    unsigned short u = h_raw[threadIdx.x & 63];
    int e = (u >> 7) & 0xFF;
    unsigned long long m = __ballot(e >= 118 && e <= 134);
    return __popcll(m) < 48;
}
static __device__ __forceinline__ bool detect_adj8(const unsigned char* adj_raw) {
    int l = threadIdx.x & 63;
    unsigned char v = (unsigned char)(adj_raw[l * 4 + 1] | adj_raw[l * 4 + 2] |
                                      adj_raw[l * 4 + 3]);
    unsigned long long m = __ballot(v != 0);
    return __popcll(m) > 8;
}

// ---------------------------------------------------------------------------
// K_prep (single launch): [0,3072) h->bf16; [3072,4224) w transpose;
// [4224,4352) zero attn acc; [4352] a_src/a_dst/bias -> f32
// ---------------------------------------------------------------------------
#define NB_H   3072   // BS*NN*FIN / 2048
#define NB_W   1152   // (FIN/32)*(FOUT/32)*NH
#define NB_Z   128    // 2*BS*NH*NN / 256
__global__ __launch_bounds__(256) void k_prep(
    const void* __restrict__ hr, unsigned short* __restrict__ h_bf,
    const void* __restrict__ wr, unsigned short* __restrict__ wt_b,
    const void* __restrict__ as_raw, const void* __restrict__ ad_raw,
    const void* __restrict__ b_raw,
    float* __restrict__ asf, float* __restrict__ adf, float* __restrict__ bff,
    float* __restrict__ attn_acc)
{
    __shared__ float tile[32][33];
    int bi = blockIdx.x;
    int t = threadIdx.x;
    if (bi < NB_H) {
        bool isf = detect_isf32((const unsigned short*)hr);
        int base = (bi * 256 + t) * 8;
        if (isf) {
            float4 f0 = *((const float4*)((const float*)hr + base));
            float4 f1 = *((const float4*)((const float*)hr + base + 4));
            unsigned short v[8] = { f2bits(f0.x), f2bits(f0.y), f2bits(f0.z), f2bits(f0.w),
                                    f2bits(f1.x), f2bits(f1.y), f2bits(f1.z), f2bits(f1.w) };
            *(uint4*)(h_bf + base) = *(const uint4*)v;
        } else {
            *(uint4*)(h_bf + base) = *(const uint4*)((const unsigned short*)hr + base);
        }
        return;
    }
    if (bi < NB_H + NB_W) {
        bool isf = detect_isf32((const unsigned short*)hr);
        int wb = bi - NB_H;
        int h  = wb / 576;           // (FIN/32)*(FOUT/32) = 576
        int rem = wb % 576;
        int f0 = (rem % 24) * 32;
        int o0 = (rem / 24) * 32;
        int tx = t & 31, ty = t >> 5;     // 32 x 8
        #pragma unroll
        for (int r = 0; r < 4; ++r) {
            int fl = ty * 4 + r;
            size_t idx = (size_t)h * FIN * FOUT + (size_t)(f0 + fl) * FOUT + (o0 + tx);
            tile[fl][tx] = isf ? ((const float*)wr)[idx]
                               : bits2f(((const unsigned short*)wr)[idx]);
        }
        __syncthreads();
        #pragma unroll
        for (int r = 0; r < 4; ++r) {
            int ol = ty * 4 + r;
            size_t oidx = (size_t)h * FOUT * FIN + (size_t)(o0 + ol) * FIN + (f0 + tx);
            wt_b[oidx] = f2bits(tile[tx][ol]);
        }
        return;
    }
    if (bi < NB_H + NB_W + NB_Z) {
        attn_acc[(bi - NB_H - NB_W) * 256 + t] = 0.f;
        return;
    }
    bool isf = detect_isf32((const unsigned short*)hr);
    for (int i = t; i < NH * FOUT; i += 256) {
        asf[i] = isf ? ((const float*)as_raw)[i] : bits2f(((const unsigned short*)as_raw)[i]);
        adf[i] = isf ? ((const float*)ad_raw)[i] : bits2f(((const unsigned short*)ad_raw)[i]);
    }
    for (int i = t; i < FOUT; i += 256)
        bff[i] = isf ? ((const float*)b_raw)[i] : bits2f(((const unsigned short*)b_raw)[i]);
}

// ---------------------------------------------------------------------------
// K1: hpT[bh][o][n] = sum_f h[b][n][f]*w[h][f][o]; fused attn_src/dst epilogue
// Proven 128x128/BK64/4-wave structure (rounds 1-7,12: never the bottleneck).
// XOR swizzle: slot cc of row r holds global chunk (cc ^ (r&7)); conflict-free.
// ---------------------------------------------------------------------------
#define BM 128
#define BN 128
#define BK 64
#define NXB (NN / BM)      // 16
#define NYB (FOUT / BN)    // 6
#define BLKS_PER_BATCH (NXB * NYB)  // 96
#define GEMM_GRID (BLKS_PER_BATCH * BS * NH)  // 768

__global__ __launch_bounds__(256) void k_gemm_hw(
    const unsigned short* __restrict__ hh,
    const unsigned short* __restrict__ wh,
    unsigned short* __restrict__ hpT,
    const float* __restrict__ asf, const float* __restrict__ adf,
    float* __restrict__ attn_src, float* __restrict__ attn_dst)
{
    int lid = blockIdx.x;
    int ib  = lid & 7;                 // batch (b*NH+h) == XCD
    int rem = lid >> 3;                // 0..95
    int i0  = (rem & 15) * BM;
    int o0  = (rem >> 4) * BN;
    int b  = ib / NH, hd = ib % NH;
    const unsigned short* A  = hh + (size_t)b  * NN * FIN;
    const unsigned short* Bt = wh + (size_t)hd * FOUT * FIN;
    unsigned short*       C  = hpT + (size_t)ib * FOUT * NN;

    __shared__ __align__(16) unsigned short As[BM * BK];
    __shared__ __align__(16) unsigned short Bs[BN * BK];

    int t = threadIdx.x;
    int lane = t & 63, wave = t >> 6;
    int wm = (wave & 1) * 64, wn = (wave >> 1) * 64;
    int lm = lane & 15, quad = lane >> 4;
    int rr = lane >> 3;                       // staging row 0..7
    int cc = lane & 7;                        // staging slot 0..7
    int gc = cc ^ rr;                         // global chunk at this slot
    int e  = lm & 7;                          // read-side row parity

    float4v acc[4][4] = {};

    for (int k0 = 0; k0 < FIN; k0 += BK) {
        __syncthreads();
        #pragma unroll
        for (int p = 0; p < 4; ++p) {
            int r0 = wave * 32 + p * 8;
            async_copy16(&As[r0 * BK], A  + (size_t)(i0 + r0 + rr) * FIN + k0 + gc * 8);
            async_copy16(&Bs[r0 * BK], Bt + (size_t)(o0 + r0 + rr) * FIN + k0 + gc * 8);
        }
        __syncthreads();
        #pragma unroll
        for (int kk = 0; kk < 2; ++kk) {
            int slot = ((kk << 2) | quad) ^ e;
            short8 fa[4], fb[4];
            #pragma unroll
            for (int mt = 0; mt < 4; ++mt)
                fa[mt] = *(const short8*)&As[(wm + mt * 16 + lm) * BK + slot * 8];
            #pragma unroll
            for (int nt = 0; nt < 4; ++nt)
                fb[nt] = *(const short8*)&Bs[(wn + nt * 16 + lm) * BK + slot * 8];
            #pragma unroll
            for (int mt = 0; mt < 4; ++mt)
                #pragma unroll
                for (int nt = 0; nt < 4; ++nt)
                    acc[mt][nt] = __builtin_amdgcn_mfma_f32_16x16x32_bf16(
                        fa[mt], fb[nt], acc[mt][nt], 0, 0, 0);
        }
    }

    // epilogue: store hpT + fused tanh-dot partials for attn_src/dst
    float asv[4], adv[4];
    #pragma unroll
    for (int nt = 0; nt < 4; ++nt) {
        int o = o0 + wn + nt * 16 + lm;
        asv[nt] = asf[hd * FOUT + o];
        adv[nt] = adf[hd * FOUT + o];
    }
    #pragma unroll
    for (int mt = 0; mt < 4; ++mt) {
        float ps[4] = {0.f, 0.f, 0.f, 0.f};
        float pd[4] = {0.f, 0.f, 0.f, 0.f};
        #pragma unroll
        for (int nt = 0; nt < 4; ++nt) {
            int node = i0 + wm + mt * 16 + quad * 4;
            int o    = o0 + wn + nt * 16 + lm;
            ushort4 v;
            v.x = f2bits(acc[mt][nt][0]);
            v.y = f2bits(acc[mt][nt][1]);
            v.z = f2bits(acc[mt][nt][2]);
            v.w = f2bits(acc[mt][nt][3]);
            *(ushort4*)&C[(size_t)o * NN + node] = v;
            #pragma unroll
            for (int r = 0; r < 4; ++r) {
                float tv = fast_tanh(acc[mt][nt][r]);
                ps[r] += tv * asv[nt];
                pd[r] += tv * adv[nt];
            }
        }
        #pragma unroll
        for (int r = 0; r < 4; ++r) {
            float s = ps[r], d = pd[r];
            #pragma unroll
            for (int off = 1; off <= 8; off <<= 1) {
                s += __shfl_xor(s, off);
                d += __shfl_xor(d, off);
            }
            if (lm == 0) {
                int node = i0 + wm + mt * 16 + quad * 4 + r;
                atomicAdd(&attn_src[ib * NN + node], s);
                atomicAdd(&attn_dst[ib * NN + node], d);
            }
        }
    }
}

// ---------------------------------------------------------------------------
// K3': row stats ONLY (m_i, 1/sum_i) — P is no longer materialized.
// Same reductions as the old k_softmax_p, minus the 67MB P write.
// ---------------------------------------------------------------------------
__global__ __launch_bounds__(256) void k_softmax_stats(
    const float* __restrict__ attn_src, const float* __restrict__ attn_dst,
    const void* __restrict__ adj_raw,
    float2* __restrict__ minv)
{
    int blk = blockIdx.x;                     // b*NN + i
    int i = blk & (NN - 1);
    int b = blk >> 11;
    bool is8 = detect_adj8((const unsigned char*)adj_raw);
    int t = threadIdx.x;
    int lane = t & 63, wave = t >> 6;
    int j0 = t * 8;

    bool keep[8];
    if (is8) {
        const unsigned char* arow = (const unsigned char*)adj_raw + ((size_t)b * NN + i) * NN;
        uint2 v = *(const uint2*)(arow + j0);
        #pragma unroll
        for (int r = 0; r < 8; ++r) {
            unsigned int w = (r < 4) ? v.x : v.y;
            keep[r] = ((w >> ((r & 3) * 8)) & 0xFFu) != 0;
        }
    } else {
        const int* arow = (const int*)adj_raw + ((size_t)b * NN + i) * NN;
        int4 v0 = *(const int4*)(arow + j0);
        int4 v1 = *(const int4*)(arow + j0 + 4);
        keep[0] = v0.x != 0; keep[1] = v0.y != 0; keep[2] = v0.z != 0; keep[3] = v0.w != 0;
        keep[4] = v1.x != 0; keep[5] = v1.y != 0; keep[6] = v1.z != 0; keep[7] = v1.w != 0;
    }
    #pragma unroll
    for (int r = 0; r < 8; ++r) keep[r] = keep[r] || (j0 + r == i);

    __shared__ float redm[NH][4], reds[NH][4];
    int bh0 = b * NH;
    float src0 = attn_src[(size_t)bh0 * NN + i];
    float src1 = attn_src[(size_t)(bh0 + 1) * NN + i];
    const float* drow0 = attn_dst + (size_t)bh0 * NN;
    const float* drow1 = attn_dst + (size_t)(bh0 + 1) * NN;
    float4 a0 = *(const float4*)(drow0 + j0);
    float4 a1 = *(const float4*)(drow0 + j0 + 4);
    float4 c0 = *(const float4*)(drow1 + j0);
    float4 c1 = *(const float4*)(drow1 + j0 + 4);
    float dj0[8] = { a0.x, a0.y, a0.z, a0.w, a1.x, a1.y, a1.z, a1.w };
    float dj1[8] = { c0.x, c0.y, c0.z, c0.w, c1.x, c1.y, c1.z, c1.w };

    float s0[8], s1[8];
    float lm0 = -1e30f, lm1 = -1e30f;
    #pragma unroll
    for (int r = 0; r < 8; ++r) {
        float sc0 = src0 + dj0[r];
        sc0 = sc0 >= 0.f ? sc0 : NEG_SLOPE * sc0;
        s0[r] = keep[r] ? sc0 : -1e30f;
        lm0 = fmaxf(lm0, s0[r]);
        float sc1 = src1 + dj1[r];
        sc1 = sc1 >= 0.f ? sc1 : NEG_SLOPE * sc1;
        s1[r] = keep[r] ? sc1 : -1e30f;
        lm1 = fmaxf(lm1, s1[r]);
    }
    #pragma unroll
    for (int off = 32; off > 0; off >>= 1) {
        lm0 = fmaxf(lm0, __shfl_xor(lm0, off));
        lm1 = fmaxf(lm1, __shfl_xor(lm1, off));
    }
    if (lane == 0) { redm[0][wave] = lm0; redm[1][wave] = lm1; }
    __syncthreads();
    float m0 = fmaxf(fmaxf(redm[0][0], redm[0][1]), fmaxf(redm[0][2], redm[0][3]));
    float m1 = fmaxf(fmaxf(redm[1][0], redm[1][1]), fmaxf(redm[1][2], redm[1][3]));

    float ls0 = 0.f, ls1 = 0.f;
    #pragma unroll
    for (int r = 0; r < 8; ++r) {
        ls0 += __expf(s0[r] - m0);
        ls1 += __expf(s1[r] - m1);
    }
    #pragma unroll
    for (int off = 32; off > 0; off >>= 1) {
        ls0 += __shfl_xor(ls0, off);
        ls1 += __shfl_xor(ls1, off);
    }
    if (lane == 0) { reds[0][wave] = ls0; reds[1][wave] = ls1; }
    __syncthreads();
    if (t == 0) {
        float inv0 = 1.0f / (reds[0][0] + reds[0][1] + reds[0][2] + reds[0][3]);
        float inv1 = 1.0f / (reds[1][0] + reds[1][1] + reds[1][2] + reds[1][3]);
        minv[(size_t)bh0 * NN + i]       = make_float2(m0, inv0);
        minv[(size_t)(bh0 + 1) * NN + i] = make_float2(m1, inv1);
    }
}

// ---------------------------------------------------------------------------
// K4 (FUSED): out[bh][i][o] = sum_j P[i][j]*hpT[o][j] + bias[o], where
// P[i][j] = keep ? exp(leaky(src_i+dst_j) - m_i) * inv_i : 0 is computed
// ON THE FLY into the LDS A-tile (no 67MB P round-trip).
// Skeleton = round-12's measured 16-wave v6 (2 phases x 12 MFMA, barrier
// pairs, setprio). A: 2-slot; thread t computes rows t>>3 and t>>3+128,
// chunk pgc=(t&7)^((t>>3)&7) -> writes slot t&7 (same XOR layout as the old
// gload_lds staging; MFMA read side untouched). adj/dst loads issued at
// tile top (issue-early), P computed + ds_write after P1's MFMA
// (consume-late); per-wave vmcnt(0)+lgkmcnt(0) then barrier at tile end
// makes both B gloads and the A ds_writes visible. B: 2-slot, gloads on
// waves 0-7 as before. Hazards: A/B slot WAR separated by >=2 barriers;
// RAW by the per-wave drain + barrier.
// ---------------------------------------------------------------------------
#define BM2 256
#define BN2 192
#define BK2 64
#define NT2 (NN / BK2)     // 32 K-tiles
#define GRID2 (8 * (NN / BM2) * (FOUT / BN2))   // 8 * 8 * 4 = 256

__global__ __launch_bounds__(1024, 4) void k_gemm_out(
    const float2* __restrict__ minv,
    const float* __restrict__ attn_src, const float* __restrict__ attn_dst,
    const void* __restrict__ adj_raw,
    const unsigned short* __restrict__ hpT,
    const float* __restrict__ bf,
    void* __restrict__ outp, const unsigned short* __restrict__ h_raw)
{
    bool isf = detect_isf32(h_raw);
    bool is8 = detect_adj8((const unsigned char*)adj_raw);
    int lid = blockIdx.x;
    int ib  = lid & 7;                 // batch == XCD (256 % 8 == 0, bijective)
    int rem = lid >> 3;                // 0..31
    int i0  = (rem & 7) * BM2;         // 8 i-tiles
    int o0  = (rem >> 3) * BN2;        // 4 o-tiles
    int b   = ib / NH;
    const unsigned short* Bt = hpT + (size_t)ib * FOUT * NN;
    const float* dstp = attn_dst + (size_t)ib * NN;

    __shared__ __align__(16) unsigned short As[2][BM2 * BK2];   // 2 x 32KB
    __shared__ __align__(16) unsigned short Bs[2][BN2 * BK2];   // 2 x 24KB

    int t = threadIdx.x;
    int lane = t & 63, wave = t >> 6;          // 16 waves
    int wr = wave >> 2, wc = wave & 3;         // 4 x 4
    int wm = wr * 64, wn = wc * 48;
    int lm = lane & 15, quad = lane >> 4;
    int e  = lm & 7;
    int rr = lane >> 3, cc = lane & 7, gc = cc ^ rr;
    bool prod = (wave < 8);                    // B staging waves

    // P-compute decomposition: rows pr, pr+128; chunk pgc -> slot pcc
    int pr  = t >> 3;                          // 0..127
    int pcc = t & 7;
    int pgc = pcc ^ (pr & 7);
    int i1 = i0 + pr, i2 = i1 + 128;
    float srcR1 = attn_src[(size_t)ib * NN + i1];
    float srcR2 = attn_src[(size_t)ib * NN + i2];
    float2 q1 = minv[(size_t)ib * NN + i1];    // {m, inv}
    float2 q2 = minv[(size_t)ib * NN + i2];
    int esz = is8 ? 1 : 4;
    const char* ab1 = (const char*)adj_raw + ((size_t)b * NN + i1) * NN * esz;
    const char* ab2 = (const char*)adj_raw + ((size_t)b * NN + i2) * NN * esz;

    float4v acc[4][3] = {};

    auto stageB = [&](int slot, int q, int kt) {
        int r0 = q * 64 + wave * 8;
        async_copy16(&Bs[slot][r0 * BK2],
                     Bt + (size_t)(o0 + r0 + rr) * NN + kt * BK2 + gc * 8);
    };
    auto kmask8 = [](uint2 c) -> unsigned {
        unsigned m = 0;
        #pragma unroll
        for (int r = 0; r < 8; ++r) {
            unsigned w = (r < 4) ? c.x : c.y;
            if ((w >> ((r & 3) * 8)) & 0xFFu) m |= 1u << r;
        }
        return m;
    };
    auto kmask32 = [](int4 a, int4 bq) -> unsigned {
        return (unsigned)((a.x != 0)       | ((a.y != 0) << 1) |
                          ((a.z != 0) << 2) | ((a.w != 0) << 3) |
                          ((bq.x != 0) << 4) | ((bq.y != 0) << 5) |
                          ((bq.z != 0) << 6) | ((bq.w != 0) << 7));
    };
    auto writeP = [&](unsigned short* dl, int j0n, float4 d0, float4 d1,
                      unsigned kb1, unsigned kb2) {
        float dj[8] = { d0.x, d0.y, d0.z, d0.w, d1.x, d1.y, d1.z, d1.w };
        unsigned short o1[8], o2[8];
        #pragma unroll
        for (int r2 = 0; r2 < 8; ++r2) {
            float s1 = srcR1 + dj[r2];
            s1 = s1 >= 0.f ? s1 : NEG_SLOPE * s1;
            bool k1 = ((kb1 >> r2) & 1u) || (j0n + r2 == i1);
            o1[r2] = k1 ? f2bits(__expf(s1 - q1.x) * q1.y) : (unsigned short)0;
            float s2 = srcR2 + dj[r2];
            s2 = s2 >= 0.f ? s2 : NEG_SLOPE * s2;
            bool k2 = ((kb2 >> r2) & 1u) || (j0n + r2 == i2);
            o2[r2] = k2 ? f2bits(__expf(s2 - q2.x) * q2.y) : (unsigned short)0;
        }
        uint4 w1, w2;
        w1.x = ((unsigned)o1[1] << 16) | o1[0]; w1.y = ((unsigned)o1[3] << 16) | o1[2];
        w1.z = ((unsigned)o1[5] << 16) | o1[4]; w1.w = ((unsigned)o1[7] << 16) | o1[6];
        w2.x = ((unsigned)o2[1] << 16) | o2[0]; w2.y = ((unsigned)o2[3] << 16) | o2[2];
        w2.z = ((unsigned)o2[5] << 16) | o2[4]; w2.w = ((unsigned)o2[7] << 16) | o2[6];
        *(uint4*)&dl[pr * BK2 + pcc * 8] = w1;
        *(uint4*)&dl[(pr + 128) * BK2 + pcc * 8] = w2;
    };

    // prologue: B(0) gloads + compute P(0) into As[0]
    if (prod) { stageB(0, 0, 0); stageB(0, 1, 0); stageB(0, 2, 0); }
    {
        int j0n = pgc * 8;                     // kt = 0
        float4 d0 = *(const float4*)(dstp + j0n);
        float4 d1 = *(const float4*)(dstp + j0n + 4);
        unsigned kb1, kb2;
        if (is8) {
            kb1 = kmask8(*(const uint2*)(ab1 + j0n));
            kb2 = kmask8(*(const uint2*)(ab2 + j0n));
        } else {
            kb1 = kmask32(*(const int4*)(ab1 + 4 * j0n),
                          *(const int4*)(ab1 + 4 * j0n + 16));
            kb2 = kmask32(*(const int4*)(ab2 + 4 * j0n),
                          *(const int4*)(ab2 + 4 * j0n + 16));
        }
        writeP(As[0], j0n, d0, d1, kb1, kb2);
    }
    asm volatile("s_waitcnt vmcnt(0) lgkmcnt(0)" ::: "memory");
    __builtin_amdgcn_s_barrier();

    short8 fa[2][2];   // A frags: 2 mt of current phase, 2 k-chunks
    short8 fb[3][2];   // B frags: all 3 nt, 2 k-chunks (live whole tile)

    for (int u = 0; u < NT2; ++u) {
        int cur = u & 1, nxt = cur ^ 1;
        bool more = (u < NT2 - 1);
        const unsigned short* Ac = As[cur];
        const unsigned short* Bc = Bs[cur];
        int j0n = (u + 1) * BK2 + pgc * 8;

        // issue-early loads for tile u+1 (regs); B gloads (waves 0-7)
        float4 d0, d1; uint2 c1, c2; unsigned kb1 = 0, kb2 = 0;
        if (more) {
            d0 = *(const float4*)(dstp + j0n);
            d1 = *(const float4*)(dstp + j0n + 4);
            if (is8) {
                c1 = *(const uint2*)(ab1 + j0n);
                c2 = *(const uint2*)(ab2 + j0n);
            } else {   // eager mask convert (bounds VGPR; int32 path only)
                kb1 = kmask32(*(const int4*)(ab1 + 4 * j0n),
                              *(const int4*)(ab1 + 4 * j0n + 16));
                kb2 = kmask32(*(const int4*)(ab2 + 4 * j0n),
                              *(const int4*)(ab2 + 4 * j0n + 16));
            }
        }
        if (prod && more) { stageB(nxt, 0, u + 1); stageB(nxt, 1, u + 1);
                            stageB(nxt, 2, u + 1); }

        // ---- P0: read fb(6) + fa mt0-1(4); 12 MFMA
        #pragma unroll
        for (int nt = 0; nt < 3; ++nt)
            #pragma unroll
            for (int kk = 0; kk < 2; ++kk)
                fb[nt][kk] = *(const short8*)&Bc[(wn + nt * 16 + lm) * BK2 +
                                                 ((((kk << 2) | quad) ^ e) * 8)];
        #pragma unroll
        for (int mt = 0; mt < 2; ++mt)
            #pragma unroll
            for (int kk = 0; kk < 2; ++kk)
                fa[mt][kk] = *(const short8*)&Ac[(wm + mt * 16 + lm) * BK2 +
                                                 ((((kk << 2) | quad) ^ e) * 8)];
        __builtin_amdgcn_s_barrier();
        __builtin_amdgcn_s_setprio(1);
        #pragma unroll
        for (int mt = 0; mt < 2; ++mt)
            #pragma unroll
            for (int nt = 0; nt < 3; ++nt)
                #pragma unroll
                for (int kk = 0; kk < 2; ++kk)
                    acc[mt][nt] = __builtin_amdgcn_mfma_f32_16x16x32_bf16(
                        fa[mt][kk], fb[nt][kk], acc[mt][nt], 0, 0, 0);
        __builtin_amdgcn_s_setprio(0);
        __builtin_amdgcn_s_barrier();

        // ---- P1: read fa mt2-3; 12 MFMA; compute+write P(u+1); drain; barrier
        #pragma unroll
        for (int mt = 0; mt < 2; ++mt)
            #pragma unroll
            for (int kk = 0; kk < 2; ++kk)
                fa[mt][kk] = *(const short8*)&Ac[(wm + 32 + mt * 16 + lm) * BK2 +
                                                 ((((kk << 2) | quad) ^ e) * 8)];
        __builtin_amdgcn_s_barrier();
        __builtin_amdgcn_s_setprio(1);
        #pragma unroll
        for (int mt = 0; mt < 2; ++mt)
            #pragma unroll
            for (int nt = 0; nt < 3; ++nt)
                #pragma unroll
                for (int kk = 0; kk < 2; ++kk)
                    acc[2 + mt][nt] = __builtin_amdgcn_mfma_f32_16x16x32_bf16(
                        fa[mt][kk], fb[nt][kk], acc[2 + mt][nt], 0, 0, 0);
        __builtin_amdgcn_s_setprio(0);
        if (more) {
            if (is8) { kb1 = kmask8(c1); kb2 = kmask8(c2); }
            writeP(As[nxt], j0n, d0, d1, kb1, kb2);
        }
        asm volatile("s_waitcnt vmcnt(0) lgkmcnt(0)" ::: "memory");
        __builtin_amdgcn_s_barrier();
    }

    // epilogue: per-wave 64x48 region
    if (isf) {
        float* C = (float*)outp + (size_t)ib * NN * FOUT;
        #pragma unroll
        for (int nt = 0; nt < 3; ++nt) {
            int o = o0 + wn + nt * 16 + lm;
            float bv = bf[o];
            #pragma unroll
            for (int mt = 0; mt < 4; ++mt) {
                int i = i0 + wm + mt * 16 + quad * 4;
                #pragma unroll
                for (int r = 0; r < 4; ++r)
                    C[(size_t)(i + r) * FOUT + o] = acc[mt][nt][r] + bv;
            }
        }
    } else {
        unsigned short* C = (unsigned short*)outp + (size_t)ib * NN * FOUT;
        #pragma unroll
        for (int nt = 0; nt < 3; ++nt) {
            int o = o0 + wn + nt * 16 + lm;
            float bv = bf[o];
            #pragma unroll
            for (int mt = 0; mt < 4; ++mt) {
                int i = i0 + wm + mt * 16 + quad * 4;
                #pragma unroll
                for (int r = 0; r < 4; ++r)
                    C[(size_t)(i + r) * FOUT + o] = f2bits(acc[mt][nt][r] + bv);
            }
        }
    }
}

// ---------------------------------------------------------------------------
extern "C" void kernel_launch(void* const* d_in, const int* in_sizes, int n_in,
                              void* d_out, int out_size, void* d_ws, size_t ws_size,
                              hipStream_t stream)
{
    const void* h_raw   = d_in[0];
    const void* adj_raw = d_in[1];
    const void* w_raw   = d_in[2];
    const void* as_raw  = d_in[3];
    const void* ad_raw  = d_in[4];
    const void* b_raw   = d_in[5];

    char* ws = (char*)d_ws;
    size_t off = 0;
    unsigned short* hpT = (unsigned short*)(ws + off); off += (size_t)BS * NH * FOUT * NN * 2;
    float* asr = (float*)(ws + off);            off += (size_t)BS * NH * NN * 4;
    float* ads = (float*)(ws + off);            off += (size_t)BS * NH * NN * 4;
    unsigned short* h_bf = (unsigned short*)(ws + off); off += (size_t)BS * NN * FIN * 2;
    unsigned short* wt_b = (unsigned short*)(ws + off); off += (size_t)NH * FOUT * FIN * 2;
    float* asf = (float*)(ws + off);            off += (size_t)NH * FOUT * 4;
    float* adf = (float*)(ws + off);            off += (size_t)NH * FOUT * 4;
    float* bff = (float*)(ws + off);            off += 4096;
    float2* minv = (float2*)(ws + off);         off += (size_t)BS * NH * NN * 8;

    k_prep<<<NB_H + NB_W + NB_Z + 1, 256, 0, stream>>>(
        h_raw, h_bf, w_raw, wt_b, as_raw, ad_raw, b_raw, asf, adf, bff, asr);
    k_gemm_hw<<<dim3(GEMM_GRID), 256, 0, stream>>>(
        h_bf, wt_b, hpT, asf, adf, asr, ads);
    k_softmax_stats<<<dim3(BS * NN), 256, 0, stream>>>(asr, ads, adj_raw, minv);
    k_gemm_out<<<dim3(GRID2), 1024, 0, stream>>>(
        minv, asr, ads, adj_raw, hpT, bff, d_out, (const unsigned short*)h_raw);
}

// Round 14
// 242.451 us; speedup vs baseline: 2.0607x; 2.0607x over previous
//
#include <hip/hip_runtime.h>
#include <hip/hip_bf16.h>
#include <cstdint>
#include <cstddef>

#define BS   4
#define NN   2048
#define NH   2
#define FIN  768
#define FOUT 768
#define NEG_SLOPE 0.2f

typedef __attribute__((ext_vector_type(8))) short short8;
typedef __attribute__((ext_vector_type(4))) float float4v;

static __device__ __forceinline__ float bits2f(unsigned short u) {
    union { unsigned int i; float f; } v; v.i = ((unsigned int)u) << 16; return v.f;
}
// RNE fp32 -> bf16 bits
static __device__ __forceinline__ unsigned short f2bits(float f) {
    union { float f; unsigned int i; } v; v.f = f;
    unsigned int x = v.i;
    unsigned int r = x + 0x7fffu + ((x >> 16) & 1u);
    return (unsigned short)(r >> 16);
}
// fast tanh via hardware exp; rel err ~1e-6
static __device__ __forceinline__ float fast_tanh(float x) {
    float xc = fminf(fmaxf(x, -20.f), 20.f);
    float e = __expf(2.f * xc);
    return (e - 1.f) / (e + 1.f);
}
// async global->LDS, 16B per lane; lds base wave-uniform, lane lands at +lane*16
static __device__ __forceinline__ void async_copy16(void* lds, const void* g) {
    __builtin_amdgcn_global_load_lds(
        (const __attribute__((address_space(1))) unsigned int*)g,
        (__attribute__((address_space(3))) unsigned int*)lds, 16, 0, 0);
}

// Per-block dtype detection (wave ballot; uniform result)
static __device__ __forceinline__ bool detect_isf32(const unsigned short* h_raw) {
    unsigned short u = h_raw[threadIdx.x & 63];
    int e = (u >> 7) & 0xFF;
    unsigned long long m = __ballot(e >= 118 && e <= 134);
    return __popcll(m) < 48;
}
static __device__ __forceinline__ bool detect_adj8(const unsigned char* adj_raw) {
    int l = threadIdx.x & 63;
    unsigned char v = (unsigned char)(adj_raw[l * 4 + 1] | adj_raw[l * 4 + 2] |
                                      adj_raw[l * 4 + 3]);
    unsigned long long m = __ballot(v != 0);
    return __popcll(m) > 8;
}

// ---------------------------------------------------------------------------
// K_prep (single launch): [0,3072) h->bf16; [3072,4224) w transpose;
// [4224,4352) zero attn acc; [4352] a_src/a_dst/bias -> f32
// ---------------------------------------------------------------------------
#define NB_H   3072   // BS*NN*FIN / 2048
#define NB_W   1152   // (FIN/32)*(FOUT/32)*NH
#define NB_Z   128    // 2*BS*NH*NN / 256
__global__ __launch_bounds__(256) void k_prep(
    const void* __restrict__ hr, unsigned short* __restrict__ h_bf,
    const void* __restrict__ wr, unsigned short* __restrict__ wt_b,
    const void* __restrict__ as_raw, const void* __restrict__ ad_raw,
    const void* __restrict__ b_raw,
    float* __restrict__ asf, float* __restrict__ adf, float* __restrict__ bff,
    float* __restrict__ attn_acc)
{
    __shared__ float tile[32][33];
    int bi = blockIdx.x;
    int t = threadIdx.x;
    if (bi < NB_H) {
        bool isf = detect_isf32((const unsigned short*)hr);
        int base = (bi * 256 + t) * 8;
        if (isf) {
            float4 f0 = *((const float4*)((const float*)hr + base));
            float4 f1 = *((const float4*)((const float*)hr + base + 4));
            unsigned short v[8] = { f2bits(f0.x), f2bits(f0.y), f2bits(f0.z), f2bits(f0.w),
                                    f2bits(f1.x), f2bits(f1.y), f2bits(f1.z), f2bits(f1.w) };
            *(uint4*)(h_bf + base) = *(const uint4*)v;
        } else {
            *(uint4*)(h_bf + base) = *(const uint4*)((const unsigned short*)hr + base);
        }
        return;
    }
    if (bi < NB_H + NB_W) {
        bool isf = detect_isf32((const unsigned short*)hr);
        int wb = bi - NB_H;
        int h  = wb / 576;           // (FIN/32)*(FOUT/32) = 576
        int rem = wb % 576;
        int f0 = (rem % 24) * 32;
        int o0 = (rem / 24) * 32;
        int tx = t & 31, ty = t >> 5;     // 32 x 8
        #pragma unroll
        for (int r = 0; r < 4; ++r) {
            int fl = ty * 4 + r;
            size_t idx = (size_t)h * FIN * FOUT + (size_t)(f0 + fl) * FOUT + (o0 + tx);
            tile[fl][tx] = isf ? ((const float*)wr)[idx]
                               : bits2f(((const unsigned short*)wr)[idx]);
        }
        __syncthreads();
        #pragma unroll
        for (int r = 0; r < 4; ++r) {
            int ol = ty * 4 + r;
            size_t oidx = (size_t)h * FOUT * FIN + (size_t)(o0 + ol) * FIN + (f0 + tx);
            wt_b[oidx] = f2bits(tile[tx][ol]);
        }
        return;
    }
    if (bi < NB_H + NB_W + NB_Z) {
        attn_acc[(bi - NB_H - NB_W) * 256 + t] = 0.f;
        return;
    }
    bool isf = detect_isf32((const unsigned short*)hr);
    for (int i = t; i < NH * FOUT; i += 256) {
        asf[i] = isf ? ((const float*)as_raw)[i] : bits2f(((const unsigned short*)as_raw)[i]);
        adf[i] = isf ? ((const float*)ad_raw)[i] : bits2f(((const unsigned short*)ad_raw)[i]);
    }
    for (int i = t; i < FOUT; i += 256)
        bff[i] = isf ? ((const float*)b_raw)[i] : bits2f(((const unsigned short*)b_raw)[i]);
}

// ---------------------------------------------------------------------------
// K1: hpT[bh][o][n] = sum_f h[b][n][f]*w[h][f][o]; fused attn_src/dst epilogue
// v2 ring template (best-measured-total config, round 11: total 244.0):
// 256x192 tile, HK=64, 8 waves (2Mx4N), acc[8][3], 4 phases/tile (12 MFMA
// each, barrier pairs), A 3-slot ring prefetched 2 tiles ahead, B dbuf 1
// ahead, ONE vmcnt(4)/tile. NT=12. Grid = 256 = full chip.
// ---------------------------------------------------------------------------
#define HM 256
#define HN 192
#define HK 64
#define HNT (FIN / HK)     // 12
#define HGRID (8 * (NN / HM) * (FOUT / HN))   // 256

__global__ __launch_bounds__(512, 2) void k_gemm_hw(
    const unsigned short* __restrict__ hh,
    const unsigned short* __restrict__ wh,
    unsigned short* __restrict__ hpT,
    const float* __restrict__ asf, const float* __restrict__ adf,
    float* __restrict__ attn_src, float* __restrict__ attn_dst)
{
    int lid = blockIdx.x;
    int ib  = lid & 7;                 // batch == XCD
    int rem = lid >> 3;                // 0..31
    int i0  = (rem & 7) * HM;
    int o0  = (rem >> 3) * HN;
    int b  = ib / NH, hd = ib % NH;
    const unsigned short* A  = hh + (size_t)b  * NN * FIN;
    const unsigned short* Bt = wh + (size_t)hd * FOUT * FIN;
    unsigned short*       C  = hpT + (size_t)ib * FOUT * NN;

    __shared__ __align__(16) unsigned short As[3][HM * HK];   // 3 x 32KB
    __shared__ __align__(16) unsigned short Bs[2][HN * HK];   // 2 x 24KB

    int t = threadIdx.x;
    int lane = t & 63, wave = t >> 6;
    int wr = wave >> 2, wc = wave & 3;
    int wm = wr * 128, wn = wc * 48;
    int lm = lane & 15, quad = lane >> 4;
    int e  = lm & 7;
    int rr = lane >> 3, cc = lane & 7, gc = cc ^ rr;

    float4v acc[8][3] = {};

    auto stageA = [&](int slot, int q, int kt) {
        int r0 = q * 64 + wave * 8;
        async_copy16(&As[slot][r0 * HK],
                     A + (size_t)(i0 + r0 + rr) * FIN + kt * HK + gc * 8);
    };
    auto stageB = [&](int slot, int q, int kt) {
        int r0 = q * 64 + wave * 8;
        async_copy16(&Bs[slot][r0 * HK],
                     Bt + (size_t)(o0 + r0 + rr) * FIN + kt * HK + gc * 8);
    };

    // prologue: A(0)->slot0, B(0)->slot0, A(1)->slot1; retire A0+B0, keep A1
    stageA(0, 0, 0); stageA(0, 1, 0); stageA(0, 2, 0); stageA(0, 3, 0);
    stageB(0, 0, 0); stageB(0, 1, 0); stageB(0, 2, 0);
    stageA(1, 0, 1); stageA(1, 1, 1); stageA(1, 2, 1); stageA(1, 3, 1);
    asm volatile("s_waitcnt vmcnt(4)" ::: "memory");
    __builtin_amdgcn_s_barrier();

    short8 fa[2][2];
    short8 fb[3][2];

    int sr = 0;
    for (int u = 0; u < HNT; ++u) {
        int sw = sr + 2; if (sw >= 3) sw -= 3;
        int sbw = (u + 1) & 1;
        bool moreA = (u < HNT - 2);
        bool moreB = (u < HNT - 1);
        const unsigned short* Ac = As[sr];
        const unsigned short* Bc = Bs[u & 1];

        // ---- P0: read fb(6) + fa mt0-1; stage B(u+1) q0,q1,q2; 12 MFMA
        #pragma unroll
        for (int nt = 0; nt < 3; ++nt)
            #pragma unroll
            for (int kk = 0; kk < 2; ++kk)
                fb[nt][kk] = *(const short8*)&Bc[(wn + nt * 16 + lm) * HK +
                                                 ((((kk << 2) | quad) ^ e) * 8)];
        #pragma unroll
        for (int mt = 0; mt < 2; ++mt)
            #pragma unroll
            for (int kk = 0; kk < 2; ++kk)
                fa[mt][kk] = *(const short8*)&Ac[(wm + mt * 16 + lm) * HK +
                                                 ((((kk << 2) | quad) ^ e) * 8)];
        if (moreB) { stageB(sbw, 0, u + 1); stageB(sbw, 1, u + 1); stageB(sbw, 2, u + 1); }
        __builtin_amdgcn_s_barrier();
        __builtin_amdgcn_s_setprio(1);
        #pragma unroll
        for (int mt = 0; mt < 2; ++mt)
            #pragma unroll
            for (int nt = 0; nt < 3; ++nt)
                #pragma unroll
                for (int kk = 0; kk < 2; ++kk)
                    acc[mt][nt] = __builtin_amdgcn_mfma_f32_16x16x32_bf16(
                        fa[mt][kk], fb[nt][kk], acc[mt][nt], 0, 0, 0);
        __builtin_amdgcn_s_setprio(0);
        __builtin_amdgcn_s_barrier();

        // ---- P1: read fa mt2-3; stage A(u+2) q0,q1; 12 MFMA
        #pragma unroll
        for (int mt = 0; mt < 2; ++mt)
            #pragma unroll
            for (int kk = 0; kk < 2; ++kk)
                fa[mt][kk] = *(const short8*)&Ac[(wm + 32 + mt * 16 + lm) * HK +
                                                 ((((kk << 2) | quad) ^ e) * 8)];
        if (moreA) { stageA(sw, 0, u + 2); stageA(sw, 1, u + 2); }
        __builtin_amdgcn_s_barrier();
        __builtin_amdgcn_s_setprio(1);
        #pragma unroll
        for (int mt = 0; mt < 2; ++mt)
            #pragma unroll
            for (int nt = 0; nt < 3; ++nt)
                #pragma unroll
                for (int kk = 0; kk < 2; ++kk)
                    acc[2 + mt][nt] = __builtin_amdgcn_mfma_f32_16x16x32_bf16(
                        fa[mt][kk], fb[nt][kk], acc[2 + mt][nt], 0, 0, 0);
        __builtin_amdgcn_s_setprio(0);
        __builtin_amdgcn_s_barrier();

        // ---- P2: read fa mt4-5; stage A(u+2) q2,q3; 12 MFMA
        #pragma unroll
        for (int mt = 0; mt < 2; ++mt)
            #pragma unroll
            for (int kk = 0; kk < 2; ++kk)
                fa[mt][kk] = *(const short8*)&Ac[(wm + 64 + mt * 16 + lm) * HK +
                                                 ((((kk << 2) | quad) ^ e) * 8)];
        if (moreA) { stageA(sw, 2, u + 2); stageA(sw, 3, u + 2); }
        __builtin_amdgcn_s_barrier();
        __builtin_amdgcn_s_setprio(1);
        #pragma unroll
        for (int mt = 0; mt < 2; ++mt)
            #pragma unroll
            for (int nt = 0; nt < 3; ++nt)
                #pragma unroll
                for (int kk = 0; kk < 2; ++kk)
                    acc[4 + mt][nt] = __builtin_amdgcn_mfma_f32_16x16x32_bf16(
                        fa[mt][kk], fb[nt][kk], acc[4 + mt][nt], 0, 0, 0);
        __builtin_amdgcn_s_setprio(0);
        __builtin_amdgcn_s_barrier();

        // ---- P3: read fa mt6-7; no stage; 12 MFMA; boundary vmcnt
        #pragma unroll
        for (int mt = 0; mt < 2; ++mt)
            #pragma unroll
            for (int kk = 0; kk < 2; ++kk)
                fa[mt][kk] = *(const short8*)&Ac[(wm + 96 + mt * 16 + lm) * HK +
                                                 ((((kk << 2) | quad) ^ e) * 8)];
        __builtin_amdgcn_s_barrier();
        __builtin_amdgcn_s_setprio(1);
        #pragma unroll
        for (int mt = 0; mt < 2; ++mt)
            #pragma unroll
            for (int nt = 0; nt < 3; ++nt)
                #pragma unroll
                for (int kk = 0; kk < 2; ++kk)
                    acc[6 + mt][nt] = __builtin_amdgcn_mfma_f32_16x16x32_bf16(
                        fa[mt][kk], fb[nt][kk], acc[6 + mt][nt], 0, 0, 0);
        __builtin_amdgcn_s_setprio(0);
        if (moreA)      asm volatile("s_waitcnt vmcnt(4)" ::: "memory");
        else if (moreB) asm volatile("s_waitcnt vmcnt(0)" ::: "memory");
        __builtin_amdgcn_s_barrier();

        sr = sr + 1 == 3 ? 0 : sr + 1;
    }

    // epilogue: store hpT + fused tanh-dot partials for attn_src/dst
    float asv[3], adv[3];
    #pragma unroll
    for (int nt = 0; nt < 3; ++nt) {
        int o = o0 + wn + nt * 16 + lm;
        asv[nt] = asf[hd * FOUT + o];
        adv[nt] = adf[hd * FOUT + o];
    }
    #pragma unroll
    for (int mt = 0; mt < 8; ++mt) {
        float ps[4] = {0.f, 0.f, 0.f, 0.f};
        float pd[4] = {0.f, 0.f, 0.f, 0.f};
        #pragma unroll
        for (int nt = 0; nt < 3; ++nt) {
            int node = i0 + wm + mt * 16 + quad * 4;
            int o    = o0 + wn + nt * 16 + lm;
            ushort4 v;
            v.x = f2bits(acc[mt][nt][0]);
            v.y = f2bits(acc[mt][nt][1]);
            v.z = f2bits(acc[mt][nt][2]);
            v.w = f2bits(acc[mt][nt][3]);
            *(ushort4*)&C[(size_t)o * NN + node] = v;
            #pragma unroll
            for (int r = 0; r < 4; ++r) {
                float tv = fast_tanh(acc[mt][nt][r]);
                ps[r] += tv * asv[nt];
                pd[r] += tv * adv[nt];
            }
        }
        #pragma unroll
        for (int r = 0; r < 4; ++r) {
            float s = ps[r], d = pd[r];
            #pragma unroll
            for (int off = 1; off <= 8; off <<= 1) {
                s += __shfl_xor(s, off);
                d += __shfl_xor(d, off);
            }
            if (lm == 0) {
                int node = i0 + wm + mt * 16 + quad * 4 + r;
                atomicAdd(&attn_src[ib * NN + node], s);
                atomicAdd(&attn_dst[ib * NN + node], d);
            }
        }
    }
}

// ---------------------------------------------------------------------------
// K3: per (b,i): read adj row once, softmax for BOTH heads in one pass
// ---------------------------------------------------------------------------
__global__ __launch_bounds__(256) void k_softmax_p(
    const float* __restrict__ attn_src, const float* __restrict__ attn_dst,
    const void* __restrict__ adj_raw,
    unsigned short* __restrict__ P)
{
    int blk = blockIdx.x;                     // b*NN + i
    int i = blk & (NN - 1);
    int b = blk >> 11;
    bool is8 = detect_adj8((const unsigned char*)adj_raw);
    int t = threadIdx.x;
    int lane = t & 63, wave = t >> 6;
    int j0 = t * 8;

    bool keep[8];
    if (is8) {
        const unsigned char* arow = (const unsigned char*)adj_raw + ((size_t)b * NN + i) * NN;
        uint2 v = *(const uint2*)(arow + j0);
        #pragma unroll
        for (int r = 0; r < 8; ++r) {
            unsigned int w = (r < 4) ? v.x : v.y;
            keep[r] = ((w >> ((r & 3) * 8)) & 0xFFu) != 0;
        }
    } else {
        const int* arow = (const int*)adj_raw + ((size_t)b * NN + i) * NN;
        int4 v0 = *(const int4*)(arow + j0);
        int4 v1 = *(const int4*)(arow + j0 + 4);
        keep[0] = v0.x != 0; keep[1] = v0.y != 0; keep[2] = v0.z != 0; keep[3] = v0.w != 0;
        keep[4] = v1.x != 0; keep[5] = v1.y != 0; keep[6] = v1.z != 0; keep[7] = v1.w != 0;
    }
    #pragma unroll
    for (int r = 0; r < 8; ++r) keep[r] = keep[r] || (j0 + r == i);

    __shared__ float redm[NH][4], reds[NH][4];
    int bh0 = b * NH;
    float src0 = attn_src[(size_t)bh0 * NN + i];
    float src1 = attn_src[(size_t)(bh0 + 1) * NN + i];
    const float* drow0 = attn_dst + (size_t)bh0 * NN;
    const float* drow1 = attn_dst + (size_t)(bh0 + 1) * NN;
    float4 a0 = *(const float4*)(drow0 + j0);
    float4 a1 = *(const float4*)(drow0 + j0 + 4);
    float4 c0 = *(const float4*)(drow1 + j0);
    float4 c1 = *(const float4*)(drow1 + j0 + 4);
    float dj0[8] = { a0.x, a0.y, a0.z, a0.w, a1.x, a1.y, a1.z, a1.w };
    float dj1[8] = { c0.x, c0.y, c0.z, c0.w, c1.x, c1.y, c1.z, c1.w };

    float s0[8], s1[8];
    float lm0 = -1e30f, lm1 = -1e30f;
    #pragma unroll
    for (int r = 0; r < 8; ++r) {
        float sc0 = src0 + dj0[r];
        sc0 = sc0 >= 0.f ? sc0 : NEG_SLOPE * sc0;
        s0[r] = keep[r] ? sc0 : -1e30f;
        lm0 = fmaxf(lm0, s0[r]);
        float sc1 = src1 + dj1[r];
        sc1 = sc1 >= 0.f ? sc1 : NEG_SLOPE * sc1;
        s1[r] = keep[r] ? sc1 : -1e30f;
        lm1 = fmaxf(lm1, s1[r]);
    }
    #pragma unroll
    for (int off = 32; off > 0; off >>= 1) {
        lm0 = fmaxf(lm0, __shfl_xor(lm0, off));
        lm1 = fmaxf(lm1, __shfl_xor(lm1, off));
    }
    if (lane == 0) { redm[0][wave] = lm0; redm[1][wave] = lm1; }
    __syncthreads();
    float m0 = fmaxf(fmaxf(redm[0][0], redm[0][1]), fmaxf(redm[0][2], redm[0][3]));
    float m1 = fmaxf(fmaxf(redm[1][0], redm[1][1]), fmaxf(redm[1][2], redm[1][3]));

    float p0[8], p1[8];
    float ls0 = 0.f, ls1 = 0.f;
    #pragma unroll
    for (int r = 0; r < 8; ++r) {
        p0[r] = __expf(s0[r] - m0); ls0 += p0[r];
        p1[r] = __expf(s1[r] - m1); ls1 += p1[r];
    }
    #pragma unroll
    for (int off = 32; off > 0; off >>= 1) {
        ls0 += __shfl_xor(ls0, off);
        ls1 += __shfl_xor(ls1, off);
    }
    if (lane == 0) { reds[0][wave] = ls0; reds[1][wave] = ls1; }
    __syncthreads();
    float inv0 = 1.0f / (reds[0][0] + reds[0][1] + reds[0][2] + reds[0][3]);
    float inv1 = 1.0f / (reds[1][0] + reds[1][1] + reds[1][2] + reds[1][3]);

    uint4 pw;
    pw.x = ((unsigned int)f2bits(p0[1] * inv0) << 16) | f2bits(p0[0] * inv0);
    pw.y = ((unsigned int)f2bits(p0[3] * inv0) << 16) | f2bits(p0[2] * inv0);
    pw.z = ((unsigned int)f2bits(p0[5] * inv0) << 16) | f2bits(p0[4] * inv0);
    pw.w = ((unsigned int)f2bits(p0[7] * inv0) << 16) | f2bits(p0[6] * inv0);
    *(uint4*)&P[((size_t)bh0 * NN + i) * NN + j0] = pw;
    pw.x = ((unsigned int)f2bits(p1[1] * inv1) << 16) | f2bits(p1[0] * inv1);
    pw.y = ((unsigned int)f2bits(p1[3] * inv1) << 16) | f2bits(p1[2] * inv1);
    pw.z = ((unsigned int)f2bits(p1[5] * inv1) << 16) | f2bits(p1[4] * inv1);
    pw.w = ((unsigned int)f2bits(p1[7] * inv1) << 16) | f2bits(p1[6] * inv1);
    *(uint4*)&P[((size_t)(bh0 + 1) * NN + i) * NN + j0] = pw;
}

// ---------------------------------------------------------------------------
// K4: out[bh][i][o] = sum_j P[i][j]*hpT[o][j] + bias[o]
// v6 (best-measured config, round 11: total 244.0): v4 ring template with
// 16 WAVES (1024 thr) = 4 waves/SIMD. A 3-slot ring depth-2 via gload_lds,
// B 2-slot, counted vmcnt(4)/tile, barrier-paired phases (2 x 12 MFMA).
// Staging on waves 0-7 only. Grid = 256 blocks; XCD-bijective decode.
// ---------------------------------------------------------------------------
#define BM2 256
#define BN2 192
#define BK2 64
#define NT2 (NN / BK2)     // 32 K-tiles
#define GRID2 (8 * (NN / BM2) * (FOUT / BN2))   // 8 * 8 * 4 = 256

__global__ __launch_bounds__(1024, 4) void k_gemm_out(
    const unsigned short* __restrict__ P,
    const unsigned short* __restrict__ hpT,
    const float* __restrict__ bf,
    void* __restrict__ outp, const unsigned short* __restrict__ h_raw)
{
    bool isf = detect_isf32(h_raw);
    int lid = blockIdx.x;
    int ib  = lid & 7;                 // batch == XCD (256 % 8 == 0, bijective)
    int rem = lid >> 3;                // 0..31
    int i0  = (rem & 7) * BM2;         // 8 i-tiles
    int o0  = (rem >> 3) * BN2;        // 4 o-tiles
    const unsigned short* A  = P   + (size_t)ib * NN * NN;
    const unsigned short* Bt = hpT + (size_t)ib * FOUT * NN;

    __shared__ __align__(16) unsigned short As[3][BM2 * BK2];   // 3 x 32KB
    __shared__ __align__(16) unsigned short Bs[2][BN2 * BK2];   // 2 x 24KB

    int t = threadIdx.x;
    int lane = t & 63, wave = t >> 6;          // 16 waves
    int wr = wave >> 2, wc = wave & 3;         // 4 x 4
    int wm = wr * 64, wn = wc * 48;
    int lm = lane & 15, quad = lane >> 4;
    int e  = lm & 7;
    int rr = lane >> 3, cc = lane & 7, gc = cc ^ rr;
    bool prod = (wave < 8);                    // staging waves

    float4v acc[4][3] = {};

    // stage 64-row group q of k-tile kt into ring slot (waves 0-7 only)
    auto stageA = [&](int slot, int q, int kt) {
        int r0 = q * 64 + wave * 8;
        async_copy16(&As[slot][r0 * BK2],
                     A + (size_t)(i0 + r0 + rr) * NN + kt * BK2 + gc * 8);
    };
    auto stageB = [&](int slot, int q, int kt) {
        int r0 = q * 64 + wave * 8;
        async_copy16(&Bs[slot][r0 * BK2],
                     Bt + (size_t)(o0 + r0 + rr) * NN + kt * BK2 + gc * 8);
    };

    // prologue: A(0)->slot0, B(0)->slot0, A(1)->slot1; retire A0+B0, keep A1
    if (prod) {
        stageA(0, 0, 0); stageA(0, 1, 0); stageA(0, 2, 0); stageA(0, 3, 0);
        stageB(0, 0, 0); stageB(0, 1, 0); stageB(0, 2, 0);
        stageA(1, 0, 1); stageA(1, 1, 1); stageA(1, 2, 1); stageA(1, 3, 1);
    }
    asm volatile("s_waitcnt vmcnt(4)" ::: "memory");
    __builtin_amdgcn_s_barrier();

    short8 fa[2][2];   // A frags: 2 mt of current phase, 2 k-chunks
    short8 fb[3][2];   // B frags: all 3 nt, 2 k-chunks (live whole tile)

    int sr = 0;                                // A read slot (u % 3)
    for (int u = 0; u < NT2; ++u) {
        int sw = sr + 2; if (sw >= 3) sw -= 3; // A write slot (u+2) % 3
        int sbw = (u + 1) & 1;                 // B write slot
        bool moreA = (u < NT2 - 2);
        bool moreB = (u < NT2 - 1);
        const unsigned short* Ac = As[sr];
        const unsigned short* Bc = Bs[u & 1];

        // ---- P0: read fb(6) + fa mt0-1(4); stage B(u+1)x3 + A(u+2)q0,q1; 12 MFMA
        #pragma unroll
        for (int nt = 0; nt < 3; ++nt)
            #pragma unroll
            for (int kk = 0; kk < 2; ++kk)
                fb[nt][kk] = *(const short8*)&Bc[(wn + nt * 16 + lm) * BK2 +
                                                 ((((kk << 2) | quad) ^ e) * 8)];
        #pragma unroll
        for (int mt = 0; mt < 2; ++mt)
            #pragma unroll
            for (int kk = 0; kk < 2; ++kk)
                fa[mt][kk] = *(const short8*)&Ac[(wm + mt * 16 + lm) * BK2 +
                                                 ((((kk << 2) | quad) ^ e) * 8)];
        if (prod && moreB) { stageB(sbw, 0, u + 1); stageB(sbw, 1, u + 1);
                             stageB(sbw, 2, u + 1); }
        if (prod && moreA) { stageA(sw, 0, u + 2); stageA(sw, 1, u + 2); }
        __builtin_amdgcn_s_barrier();
        __builtin_amdgcn_s_setprio(1);
        #pragma unroll
        for (int mt = 0; mt < 2; ++mt)
            #pragma unroll
            for (int nt = 0; nt < 3; ++nt)
                #pragma unroll
                for (int kk = 0; kk < 2; ++kk)
                    acc[mt][nt] = __builtin_amdgcn_mfma_f32_16x16x32_bf16(
                        fa[mt][kk], fb[nt][kk], acc[mt][nt], 0, 0, 0);
        __builtin_amdgcn_s_setprio(0);
        __builtin_amdgcn_s_barrier();

        // ---- P1: read fa mt2-3; stage A(u+2) q2,q3; 12 MFMA; end vmcnt
        #pragma unroll
        for (int mt = 0; mt < 2; ++mt)
            #pragma unroll
            for (int kk = 0; kk < 2; ++kk)
                fa[mt][kk] = *(const short8*)&Ac[(wm + 32 + mt * 16 + lm) * BK2 +
                                                 ((((kk << 2) | quad) ^ e) * 8)];
        if (prod && moreA) { stageA(sw, 2, u + 2); stageA(sw, 3, u + 2); }
        __builtin_amdgcn_s_barrier();
        __builtin_amdgcn_s_setprio(1);
        #pragma unroll
        for (int mt = 0; mt < 2; ++mt)
            #pragma unroll
            for (int nt = 0; nt < 3; ++nt)
                #pragma unroll
                for (int kk = 0; kk < 2; ++kk)
                    acc[2 + mt][nt] = __builtin_amdgcn_mfma_f32_16x16x32_bf16(
                        fa[mt][kk], fb[nt][kk], acc[2 + mt][nt], 0, 0, 0);
        __builtin_amdgcn_s_setprio(0);
        // boundary: retire A(u+1)x4 + B(u+1)x3, keep A(u+2)x4 in flight
        if (moreA)      asm volatile("s_waitcnt vmcnt(4)" ::: "memory");
        else if (moreB) asm volatile("s_waitcnt vmcnt(0)" ::: "memory");
        __builtin_amdgcn_s_barrier();

        sr = sr + 1 == 3 ? 0 : sr + 1;
    }

    // epilogue: per-wave 64x48 region
    if (isf) {
        float* C = (float*)outp + (size_t)ib * NN * FOUT;
        #pragma unroll
        for (int nt = 0; nt < 3; ++nt) {
            int o = o0 + wn + nt * 16 + lm;
            float bv = bf[o];
            #pragma unroll
            for (int mt = 0; mt < 4; ++mt) {
                int i = i0 + wm + mt * 16 + quad * 4;
                #pragma unroll
                for (int r = 0; r < 4; ++r)
                    C[(size_t)(i + r) * FOUT + o] = acc[mt][nt][r] + bv;
            }
        }
    } else {
        unsigned short* C = (unsigned short*)outp + (size_t)ib * NN * FOUT;
        #pragma unroll
        for (int nt = 0; nt < 3; ++nt) {
            int o = o0 + wn + nt * 16 + lm;
            float bv = bf[o];
            #pragma unroll
            for (int mt = 0; mt < 4; ++mt) {
                int i = i0 + wm + mt * 16 + quad * 4;
                #pragma unroll
                for (int r = 0; r < 4; ++r)
                    C[(size_t)(i + r) * FOUT + o] = f2bits(acc[mt][nt][r] + bv);
            }
        }
    }
}

// ---------------------------------------------------------------------------
extern "C" void kernel_launch(void* const* d_in, const int* in_sizes, int n_in,
                              void* d_out, int out_size, void* d_ws, size_t ws_size,
                              hipStream_t stream)
{
    const void* h_raw   = d_in[0];
    const void* adj_raw = d_in[1];
    const void* w_raw   = d_in[2];
    const void* as_raw  = d_in[3];
    const void* ad_raw  = d_in[4];
    const void* b_raw   = d_in[5];

    char* ws = (char*)d_ws;
    size_t off = 0;
    unsigned short* hpT = (unsigned short*)(ws + off); off += (size_t)BS * NH * FOUT * NN * 2;
    float* asr = (float*)(ws + off);            off += (size_t)BS * NH * NN * 4;
    float* ads = (float*)(ws + off);            off += (size_t)BS * NH * NN * 4;
    // union: {h_bf16, wt_bf16} live only until k_gemm_hw; P overlays after.
    size_t uoff = off;
    unsigned short* P    = (unsigned short*)(ws + uoff);
    unsigned short* h_bf = (unsigned short*)(ws + uoff); uoff += (size_t)BS * NN * FIN * 2;
    unsigned short* wt_b = (unsigned short*)(ws + uoff); uoff += (size_t)NH * FOUT * FIN * 2;
    off += (size_t)BS * NH * NN * NN * 2;       // P dominates the union
    float* asf = (float*)(ws + off);            off += (size_t)NH * FOUT * 4;
    float* adf = (float*)(ws + off);            off += (size_t)NH * FOUT * 4;
    float* bff = (float*)(ws + off);            off += 4096;

    k_prep<<<NB_H + NB_W + NB_Z + 1, 256, 0, stream>>>(
        h_raw, h_bf, w_raw, wt_b, as_raw, ad_raw, b_raw, asf, adf, bff, asr);
    k_gemm_hw<<<dim3(HGRID), 512, 0, stream>>>(
        h_bf, wt_b, hpT, asf, adf, asr, ads);
    k_softmax_p<<<dim3(BS * NN), 256, 0, stream>>>(asr, ads, adj_raw, P);
    k_gemm_out<<<dim3(GRID2), 1024, 0, stream>>>(
        P, hpT, bff, d_out, (const unsigned short*)h_raw);
}

// Round 15
// 240.453 us; speedup vs baseline: 2.0779x; 1.0083x over previous
//
#include <hip/hip_runtime.h>
#include <hip/hip_bf16.h>
#include <cstdint>
#include <cstddef>

#define BS   4
#define NN   2048
#define NH   2
#define FIN  768
#define FOUT 768
#define NEG_SLOPE 0.2f

typedef __attribute__((ext_vector_type(8))) short short8;
typedef __attribute__((ext_vector_type(4))) float float4v;

static __device__ __forceinline__ float bits2f(unsigned short u) {
    union { unsigned int i; float f; } v; v.i = ((unsigned int)u) << 16; return v.f;
}
// RNE fp32 -> bf16 bits
static __device__ __forceinline__ unsigned short f2bits(float f) {
    union { float f; unsigned int i; } v; v.f = f;
    unsigned int x = v.i;
    unsigned int r = x + 0x7fffu + ((x >> 16) & 1u);
    return (unsigned short)(r >> 16);
}
// fast tanh via hardware exp; rel err ~1e-6
static __device__ __forceinline__ float fast_tanh(float x) {
    float xc = fminf(fmaxf(x, -20.f), 20.f);
    float e = __expf(2.f * xc);
    return (e - 1.f) / (e + 1.f);
}
// async global->LDS, 16B per lane; lds base wave-uniform, lane lands at +lane*16
static __device__ __forceinline__ void async_copy16(void* lds, const void* g) {
    __builtin_amdgcn_global_load_lds(
        (const __attribute__((address_space(1))) unsigned int*)g,
        (__attribute__((address_space(3))) unsigned int*)lds, 16, 0, 0);
}

// Per-block dtype detection (wave ballot; uniform result)
static __device__ __forceinline__ bool detect_isf32(const unsigned short* h_raw) {
    unsigned short u = h_raw[threadIdx.x & 63];
    int e = (u >> 7) & 0xFF;
    unsigned long long m = __ballot(e >= 118 && e <= 134);
    return __popcll(m) < 48;
}
static __device__ __forceinline__ bool detect_adj8(const unsigned char* adj_raw) {
    int l = threadIdx.x & 63;
    unsigned char v = (unsigned char)(adj_raw[l * 4 + 1] | adj_raw[l * 4 + 2] |
                                      adj_raw[l * 4 + 3]);
    unsigned long long m = __ballot(v != 0);
    return __popcll(m) > 8;
}

// ---------------------------------------------------------------------------
// K_prep (single launch): [0,3072) h->bf16; [3072,4224) w transpose;
// [4224,4352) zero attn acc; [4352] a_src/a_dst/bias -> f32
// ---------------------------------------------------------------------------
#define NB_H   3072   // BS*NN*FIN / 2048
#define NB_W   1152   // (FIN/32)*(FOUT/32)*NH
#define NB_Z   128    // 2*BS*NH*NN / 256
__global__ __launch_bounds__(256) void k_prep(
    const void* __restrict__ hr, unsigned short* __restrict__ h_bf,
    const void* __restrict__ wr, unsigned short* __restrict__ wt_b,
    const void* __restrict__ as_raw, const void* __restrict__ ad_raw,
    const void* __restrict__ b_raw,
    float* __restrict__ asf, float* __restrict__ adf, float* __restrict__ bff,
    float* __restrict__ attn_acc)
{
    __shared__ float tile[32][33];
    int bi = blockIdx.x;
    int t = threadIdx.x;
    if (bi < NB_H) {
        bool isf = detect_isf32((const unsigned short*)hr);
        int base = (bi * 256 + t) * 8;
        if (isf) {
            float4 f0 = *((const float4*)((const float*)hr + base));
            float4 f1 = *((const float4*)((const float*)hr + base + 4));
            unsigned short v[8] = { f2bits(f0.x), f2bits(f0.y), f2bits(f0.z), f2bits(f0.w),
                                    f2bits(f1.x), f2bits(f1.y), f2bits(f1.z), f2bits(f1.w) };
            *(uint4*)(h_bf + base) = *(const uint4*)v;
        } else {
            *(uint4*)(h_bf + base) = *(const uint4*)((const unsigned short*)hr + base);
        }
        return;
    }
    if (bi < NB_H + NB_W) {
        bool isf = detect_isf32((const unsigned short*)hr);
        int wb = bi - NB_H;
        int h  = wb / 576;           // (FIN/32)*(FOUT/32) = 576
        int rem = wb % 576;
        int f0 = (rem % 24) * 32;
        int o0 = (rem / 24) * 32;
        int tx = t & 31, ty = t >> 5;     // 32 x 8
        #pragma unroll
        for (int r = 0; r < 4; ++r) {
            int fl = ty * 4 + r;
            size_t idx = (size_t)h * FIN * FOUT + (size_t)(f0 + fl) * FOUT + (o0 + tx);
            tile[fl][tx] = isf ? ((const float*)wr)[idx]
                               : bits2f(((const unsigned short*)wr)[idx]);
        }
        __syncthreads();
        #pragma unroll
        for (int r = 0; r < 4; ++r) {
            int ol = ty * 4 + r;
            size_t oidx = (size_t)h * FOUT * FIN + (size_t)(o0 + ol) * FIN + (f0 + tx);
            wt_b[oidx] = f2bits(tile[tx][ol]);
        }
        return;
    }
    if (bi < NB_H + NB_W + NB_Z) {
        attn_acc[(bi - NB_H - NB_W) * 256 + t] = 0.f;
        return;
    }
    bool isf = detect_isf32((const unsigned short*)hr);
    for (int i = t; i < NH * FOUT; i += 256) {
        asf[i] = isf ? ((const float*)as_raw)[i] : bits2f(((const unsigned short*)as_raw)[i]);
        adf[i] = isf ? ((const float*)ad_raw)[i] : bits2f(((const unsigned short*)ad_raw)[i]);
    }
    for (int i = t; i < FOUT; i += 256)
        bff[i] = isf ? ((const float*)b_raw)[i] : bits2f(((const unsigned short*)b_raw)[i]);
}

// ---------------------------------------------------------------------------
// K1: hpT[bh][o][n] = sum_f h[b][n][f]*w[h][f][o]; fused attn_src/dst epilogue
// v2 ring template (part of best-measured config: 244.0/242.5):
// 256x192 tile, HK=64, 8 waves (2Mx4N), acc[8][3], 4 phases/tile (12 MFMA
// each, barrier pairs), A 3-slot ring prefetched 2 tiles ahead, B dbuf 1
// ahead, ONE vmcnt(4)/tile. NT=12. Grid = 256 = full chip.
// ---------------------------------------------------------------------------
#define HM 256
#define HN 192
#define HK 64
#define HNT (FIN / HK)     // 12
#define HGRID (8 * (NN / HM) * (FOUT / HN))   // 256

__global__ __launch_bounds__(512, 2) void k_gemm_hw(
    const unsigned short* __restrict__ hh,
    const unsigned short* __restrict__ wh,
    unsigned short* __restrict__ hpT,
    const float* __restrict__ asf, const float* __restrict__ adf,
    float* __restrict__ attn_src, float* __restrict__ attn_dst)
{
    int lid = blockIdx.x;
    int ib  = lid & 7;                 // batch == XCD
    int rem = lid >> 3;                // 0..31
    int i0  = (rem & 7) * HM;
    int o0  = (rem >> 3) * HN;
    int b  = ib / NH, hd = ib % NH;
    const unsigned short* A  = hh + (size_t)b  * NN * FIN;
    const unsigned short* Bt = wh + (size_t)hd * FOUT * FIN;
    unsigned short*       C  = hpT + (size_t)ib * FOUT * NN;

    __shared__ __align__(16) unsigned short As[3][HM * HK];   // 3 x 32KB
    __shared__ __align__(16) unsigned short Bs[2][HN * HK];   // 2 x 24KB

    int t = threadIdx.x;
    int lane = t & 63, wave = t >> 6;
    int wr = wave >> 2, wc = wave & 3;
    int wm = wr * 128, wn = wc * 48;
    int lm = lane & 15, quad = lane >> 4;
    int e  = lm & 7;
    int rr = lane >> 3, cc = lane & 7, gc = cc ^ rr;

    float4v acc[8][3] = {};

    auto stageA = [&](int slot, int q, int kt) {
        int r0 = q * 64 + wave * 8;
        async_copy16(&As[slot][r0 * HK],
                     A + (size_t)(i0 + r0 + rr) * FIN + kt * HK + gc * 8);
    };
    auto stageB = [&](int slot, int q, int kt) {
        int r0 = q * 64 + wave * 8;
        async_copy16(&Bs[slot][r0 * HK],
                     Bt + (size_t)(o0 + r0 + rr) * FIN + kt * HK + gc * 8);
    };

    // prologue: A(0)->slot0, B(0)->slot0, A(1)->slot1; retire A0+B0, keep A1
    stageA(0, 0, 0); stageA(0, 1, 0); stageA(0, 2, 0); stageA(0, 3, 0);
    stageB(0, 0, 0); stageB(0, 1, 0); stageB(0, 2, 0);
    stageA(1, 0, 1); stageA(1, 1, 1); stageA(1, 2, 1); stageA(1, 3, 1);
    asm volatile("s_waitcnt vmcnt(4)" ::: "memory");
    __builtin_amdgcn_s_barrier();

    short8 fa[2][2];
    short8 fb[3][2];

    int sr = 0;
    for (int u = 0; u < HNT; ++u) {
        int sw = sr + 2; if (sw >= 3) sw -= 3;
        int sbw = (u + 1) & 1;
        bool moreA = (u < HNT - 2);
        bool moreB = (u < HNT - 1);
        const unsigned short* Ac = As[sr];
        const unsigned short* Bc = Bs[u & 1];

        // ---- P0: read fb(6) + fa mt0-1; stage B(u+1) q0,q1,q2; 12 MFMA
        #pragma unroll
        for (int nt = 0; nt < 3; ++nt)
            #pragma unroll
            for (int kk = 0; kk < 2; ++kk)
                fb[nt][kk] = *(const short8*)&Bc[(wn + nt * 16 + lm) * HK +
                                                 ((((kk << 2) | quad) ^ e) * 8)];
        #pragma unroll
        for (int mt = 0; mt < 2; ++mt)
            #pragma unroll
            for (int kk = 0; kk < 2; ++kk)
                fa[mt][kk] = *(const short8*)&Ac[(wm + mt * 16 + lm) * HK +
                                                 ((((kk << 2) | quad) ^ e) * 8)];
        if (moreB) { stageB(sbw, 0, u + 1); stageB(sbw, 1, u + 1); stageB(sbw, 2, u + 1); }
        __builtin_amdgcn_s_barrier();
        __builtin_amdgcn_s_setprio(1);
        #pragma unroll
        for (int mt = 0; mt < 2; ++mt)
            #pragma unroll
            for (int nt = 0; nt < 3; ++nt)
                #pragma unroll
                for (int kk = 0; kk < 2; ++kk)
                    acc[mt][nt] = __builtin_amdgcn_mfma_f32_16x16x32_bf16(
                        fa[mt][kk], fb[nt][kk], acc[mt][nt], 0, 0, 0);
        __builtin_amdgcn_s_setprio(0);
        __builtin_amdgcn_s_barrier();

        // ---- P1: read fa mt2-3; stage A(u+2) q0,q1; 12 MFMA
        #pragma unroll
        for (int mt = 0; mt < 2; ++mt)
            #pragma unroll
            for (int kk = 0; kk < 2; ++kk)
                fa[mt][kk] = *(const short8*)&Ac[(wm + 32 + mt * 16 + lm) * HK +
                                                 ((((kk << 2) | quad) ^ e) * 8)];
        if (moreA) { stageA(sw, 0, u + 2); stageA(sw, 1, u + 2); }
        __builtin_amdgcn_s_barrier();
        __builtin_amdgcn_s_setprio(1);
        #pragma unroll
        for (int mt = 0; mt < 2; ++mt)
            #pragma unroll
            for (int nt = 0; nt < 3; ++nt)
                #pragma unroll
                for (int kk = 0; kk < 2; ++kk)
                    acc[2 + mt][nt] = __builtin_amdgcn_mfma_f32_16x16x32_bf16(
                        fa[mt][kk], fb[nt][kk], acc[2 + mt][nt], 0, 0, 0);
        __builtin_amdgcn_s_setprio(0);
        __builtin_amdgcn_s_barrier();

        // ---- P2: read fa mt4-5; stage A(u+2) q2,q3; 12 MFMA
        #pragma unroll
        for (int mt = 0; mt < 2; ++mt)
            #pragma unroll
            for (int kk = 0; kk < 2; ++kk)
                fa[mt][kk] = *(const short8*)&Ac[(wm + 64 + mt * 16 + lm) * HK +
                                                 ((((kk << 2) | quad) ^ e) * 8)];
        if (moreA) { stageA(sw, 2, u + 2); stageA(sw, 3, u + 2); }
        __builtin_amdgcn_s_barrier();
        __builtin_amdgcn_s_setprio(1);
        #pragma unroll
        for (int mt = 0; mt < 2; ++mt)
            #pragma unroll
            for (int nt = 0; nt < 3; ++nt)
                #pragma unroll
                for (int kk = 0; kk < 2; ++kk)
                    acc[4 + mt][nt] = __builtin_amdgcn_mfma_f32_16x16x32_bf16(
                        fa[mt][kk], fb[nt][kk], acc[4 + mt][nt], 0, 0, 0);
        __builtin_amdgcn_s_setprio(0);
        __builtin_amdgcn_s_barrier();

        // ---- P3: read fa mt6-7; no stage; 12 MFMA; boundary vmcnt
        #pragma unroll
        for (int mt = 0; mt < 2; ++mt)
            #pragma unroll
            for (int kk = 0; kk < 2; ++kk)
                fa[mt][kk] = *(const short8*)&Ac[(wm + 96 + mt * 16 + lm) * HK +
                                                 ((((kk << 2) | quad) ^ e) * 8)];
        __builtin_amdgcn_s_barrier();
        __builtin_amdgcn_s_setprio(1);
        #pragma unroll
        for (int mt = 0; mt < 2; ++mt)
            #pragma unroll
            for (int nt = 0; nt < 3; ++nt)
                #pragma unroll
                for (int kk = 0; kk < 2; ++kk)
                    acc[6 + mt][nt] = __builtin_amdgcn_mfma_f32_16x16x32_bf16(
                        fa[mt][kk], fb[nt][kk], acc[6 + mt][nt], 0, 0, 0);
        __builtin_amdgcn_s_setprio(0);
        if (moreA)      asm volatile("s_waitcnt vmcnt(4)" ::: "memory");
        else if (moreB) asm volatile("s_waitcnt vmcnt(0)" ::: "memory");
        __builtin_amdgcn_s_barrier();

        sr = sr + 1 == 3 ? 0 : sr + 1;
    }

    // epilogue: store hpT + fused tanh-dot partials for attn_src/dst
    float asv[3], adv[3];
    #pragma unroll
    for (int nt = 0; nt < 3; ++nt) {
        int o = o0 + wn + nt * 16 + lm;
        asv[nt] = asf[hd * FOUT + o];
        adv[nt] = adf[hd * FOUT + o];
    }
    #pragma unroll
    for (int mt = 0; mt < 8; ++mt) {
        float ps[4] = {0.f, 0.f, 0.f, 0.f};
        float pd[4] = {0.f, 0.f, 0.f, 0.f};
        #pragma unroll
        for (int nt = 0; nt < 3; ++nt) {
            int node = i0 + wm + mt * 16 + quad * 4;
            int o    = o0 + wn + nt * 16 + lm;
            ushort4 v;
            v.x = f2bits(acc[mt][nt][0]);
            v.y = f2bits(acc[mt][nt][1]);
            v.z = f2bits(acc[mt][nt][2]);
            v.w = f2bits(acc[mt][nt][3]);
            *(ushort4*)&C[(size_t)o * NN + node] = v;
            #pragma unroll
            for (int r = 0; r < 4; ++r) {
                float tv = fast_tanh(acc[mt][nt][r]);
                ps[r] += tv * asv[nt];
                pd[r] += tv * adv[nt];
            }
        }
        #pragma unroll
        for (int r = 0; r < 4; ++r) {
            float s = ps[r], d = pd[r];
            #pragma unroll
            for (int off = 1; off <= 8; off <<= 1) {
                s += __shfl_xor(s, off);
                d += __shfl_xor(d, off);
            }
            if (lm == 0) {
                int node = i0 + wm + mt * 16 + quad * 4 + r;
                atomicAdd(&attn_src[ib * NN + node], s);
                atomicAdd(&attn_dst[ib * NN + node], d);
            }
        }
    }
}

// ---------------------------------------------------------------------------
// K3: per (b,i): read adj row once, softmax for BOTH heads in one pass
// ---------------------------------------------------------------------------
__global__ __launch_bounds__(256) void k_softmax_p(
    const float* __restrict__ attn_src, const float* __restrict__ attn_dst,
    const void* __restrict__ adj_raw,
    unsigned short* __restrict__ P)
{
    int blk = blockIdx.x;                     // b*NN + i
    int i = blk & (NN - 1);
    int b = blk >> 11;
    bool is8 = detect_adj8((const unsigned char*)adj_raw);
    int t = threadIdx.x;
    int lane = t & 63, wave = t >> 6;
    int j0 = t * 8;

    bool keep[8];
    if (is8) {
        const unsigned char* arow = (const unsigned char*)adj_raw + ((size_t)b * NN + i) * NN;
        uint2 v = *(const uint2*)(arow + j0);
        #pragma unroll
        for (int r = 0; r < 8; ++r) {
            unsigned int w = (r < 4) ? v.x : v.y;
            keep[r] = ((w >> ((r & 3) * 8)) & 0xFFu) != 0;
        }
    } else {
        const int* arow = (const int*)adj_raw + ((size_t)b * NN + i) * NN;
        int4 v0 = *(const int4*)(arow + j0);
        int4 v1 = *(const int4*)(arow + j0 + 4);
        keep[0] = v0.x != 0; keep[1] = v0.y != 0; keep[2] = v0.z != 0; keep[3] = v0.w != 0;
        keep[4] = v1.x != 0; keep[5] = v1.y != 0; keep[6] = v1.z != 0; keep[7] = v1.w != 0;
    }
    #pragma unroll
    for (int r = 0; r < 8; ++r) keep[r] = keep[r] || (j0 + r == i);

    __shared__ float redm[NH][4], reds[NH][4];
    int bh0 = b * NH;
    float src0 = attn_src[(size_t)bh0 * NN + i];
    float src1 = attn_src[(size_t)(bh0 + 1) * NN + i];
    const float* drow0 = attn_dst + (size_t)bh0 * NN;
    const float* drow1 = attn_dst + (size_t)(bh0 + 1) * NN;
    float4 a0 = *(const float4*)(drow0 + j0);
    float4 a1 = *(const float4*)(drow0 + j0 + 4);
    float4 c0 = *(const float4*)(drow1 + j0);
    float4 c1 = *(const float4*)(drow1 + j0 + 4);
    float dj0[8] = { a0.x, a0.y, a0.z, a0.w, a1.x, a1.y, a1.z, a1.w };
    float dj1[8] = { c0.x, c0.y, c0.z, c0.w, c1.x, c1.y, c1.z, c1.w };

    float s0[8], s1[8];
    float lm0 = -1e30f, lm1 = -1e30f;
    #pragma unroll
    for (int r = 0; r < 8; ++r) {
        float sc0 = src0 + dj0[r];
        sc0 = sc0 >= 0.f ? sc0 : NEG_SLOPE * sc0;
        s0[r] = keep[r] ? sc0 : -1e30f;
        lm0 = fmaxf(lm0, s0[r]);
        float sc1 = src1 + dj1[r];
        sc1 = sc1 >= 0.f ? sc1 : NEG_SLOPE * sc1;
        s1[r] = keep[r] ? sc1 : -1e30f;
        lm1 = fmaxf(lm1, s1[r]);
    }
    #pragma unroll
    for (int off = 32; off > 0; off >>= 1) {
        lm0 = fmaxf(lm0, __shfl_xor(lm0, off));
        lm1 = fmaxf(lm1, __shfl_xor(lm1, off));
    }
    if (lane == 0) { redm[0][wave] = lm0; redm[1][wave] = lm1; }
    __syncthreads();
    float m0 = fmaxf(fmaxf(redm[0][0], redm[0][1]), fmaxf(redm[0][2], redm[0][3]));
    float m1 = fmaxf(fmaxf(redm[1][0], redm[1][1]), fmaxf(redm[1][2], redm[1][3]));

    float p0[8], p1[8];
    float ls0 = 0.f, ls1 = 0.f;
    #pragma unroll
    for (int r = 0; r < 8; ++r) {
        p0[r] = __expf(s0[r] - m0); ls0 += p0[r];
        p1[r] = __expf(s1[r] - m1); ls1 += p1[r];
    }
    #pragma unroll
    for (int off = 32; off > 0; off >>= 1) {
        ls0 += __shfl_xor(ls0, off);
        ls1 += __shfl_xor(ls1, off);
    }
    if (lane == 0) { reds[0][wave] = ls0; reds[1][wave] = ls1; }
    __syncthreads();
    float inv0 = 1.0f / (reds[0][0] + reds[0][1] + reds[0][2] + reds[0][3]);
    float inv1 = 1.0f / (reds[1][0] + reds[1][1] + reds[1][2] + reds[1][3]);

    uint4 pw;
    pw.x = ((unsigned int)f2bits(p0[1] * inv0) << 16) | f2bits(p0[0] * inv0);
    pw.y = ((unsigned int)f2bits(p0[3] * inv0) << 16) | f2bits(p0[2] * inv0);
    pw.z = ((unsigned int)f2bits(p0[5] * inv0) << 16) | f2bits(p0[4] * inv0);
    pw.w = ((unsigned int)f2bits(p0[7] * inv0) << 16) | f2bits(p0[6] * inv0);
    *(uint4*)&P[((size_t)bh0 * NN + i) * NN + j0] = pw;
    pw.x = ((unsigned int)f2bits(p1[1] * inv1) << 16) | f2bits(p1[0] * inv1);
    pw.y = ((unsigned int)f2bits(p1[3] * inv1) << 16) | f2bits(p1[2] * inv1);
    pw.z = ((unsigned int)f2bits(p1[5] * inv1) << 16) | f2bits(p1[4] * inv1);
    pw.w = ((unsigned int)f2bits(p1[7] * inv1) << 16) | f2bits(p1[6] * inv1);
    *(uint4*)&P[((size_t)(bh0 + 1) * NN + i) * NN + j0] = pw;
}

// ---------------------------------------------------------------------------
// K4: out[bh][i][o] = sum_j P[i][j]*hpT[o][j] + bias[o]
// v7: 16-wave ring template with ONE phase per K-tile (14 b128 reads, 24
// MFMA, 1 vmcnt + 1 barrier). Rationale: at 4 waves/SIMD the LDS pipe is
// the saturated resource (~78% of tile time); the 4 barrier convergences
// (~1000 cyc/tile) are the gap to the LDS floor. Unlike round-8's failure
// (2 waves/SIMD needed the phase stagger), 4-way TLP self-staggers.
// Ring hazards at 1 barrier/tile: A read (u)%3 vs write (u+2)%3 disjoint;
// B read u&1 vs write (u+1)&1 disjoint; WAR across the barrier OK (reads
// consumed into regs before each wave's barrier). vmcnt queue unchanged:
// entering tile u outstanding A(u+1)x4; issue B(u+1)x3 -> 7, A(u+2)x4 ->
// 11; end vmcnt(4) retires A(u+1)+B(u+1). Tail: vmcnt(0) at u==NT2-2.
// Staging on waves 0-7 only. Grid = 256 blocks; XCD-bijective decode.
// ---------------------------------------------------------------------------
#define BM2 256
#define BN2 192
#define BK2 64
#define NT2 (NN / BK2)     // 32 K-tiles
#define GRID2 (8 * (NN / BM2) * (FOUT / BN2))   // 8 * 8 * 4 = 256

__global__ __launch_bounds__(1024, 4) void k_gemm_out(
    const unsigned short* __restrict__ P,
    const unsigned short* __restrict__ hpT,
    const float* __restrict__ bf,
    void* __restrict__ outp, const unsigned short* __restrict__ h_raw)
{
    bool isf = detect_isf32(h_raw);
    int lid = blockIdx.x;
    int ib  = lid & 7;                 // batch == XCD (256 % 8 == 0, bijective)
    int rem = lid >> 3;                // 0..31
    int i0  = (rem & 7) * BM2;         // 8 i-tiles
    int o0  = (rem >> 3) * BN2;        // 4 o-tiles
    const unsigned short* A  = P   + (size_t)ib * NN * NN;
    const unsigned short* Bt = hpT + (size_t)ib * FOUT * NN;

    __shared__ __align__(16) unsigned short As[3][BM2 * BK2];   // 3 x 32KB
    __shared__ __align__(16) unsigned short Bs[2][BN2 * BK2];   // 2 x 24KB

    int t = threadIdx.x;
    int lane = t & 63, wave = t >> 6;          // 16 waves
    int wr = wave >> 2, wc = wave & 3;         // 4 x 4
    int wm = wr * 64, wn = wc * 48;
    int lm = lane & 15, quad = lane >> 4;
    int e  = lm & 7;
    int rr = lane >> 3, cc = lane & 7, gc = cc ^ rr;
    bool prod = (wave < 8);                    // staging waves

    float4v acc[4][3] = {};

    // stage 64-row group q of k-tile kt into ring slot (waves 0-7 only)
    auto stageA = [&](int slot, int q, int kt) {
        int r0 = q * 64 + wave * 8;
        async_copy16(&As[slot][r0 * BK2],
                     A + (size_t)(i0 + r0 + rr) * NN + kt * BK2 + gc * 8);
    };
    auto stageB = [&](int slot, int q, int kt) {
        int r0 = q * 64 + wave * 8;
        async_copy16(&Bs[slot][r0 * BK2],
                     Bt + (size_t)(o0 + r0 + rr) * NN + kt * BK2 + gc * 8);
    };

    // prologue: A(0)->slot0, B(0)->slot0, A(1)->slot1; retire A0+B0, keep A1
    if (prod) {
        stageA(0, 0, 0); stageA(0, 1, 0); stageA(0, 2, 0); stageA(0, 3, 0);
        stageB(0, 0, 0); stageB(0, 1, 0); stageB(0, 2, 0);
        stageA(1, 0, 1); stageA(1, 1, 1); stageA(1, 2, 1); stageA(1, 3, 1);
    }
    asm volatile("s_waitcnt vmcnt(4)" ::: "memory");
    __builtin_amdgcn_s_barrier();

    short8 fa[4][2];   // A frags: all 4 mt, 2 k-chunks
    short8 fb[3][2];   // B frags: all 3 nt, 2 k-chunks

    int sr = 0;                                // A read slot (u % 3)
    for (int u = 0; u < NT2; ++u) {
        int sw = sr + 2; if (sw >= 3) sw -= 3; // A write slot (u+2) % 3
        int sbw = (u + 1) & 1;                 // B write slot
        bool moreA = (u < NT2 - 2);
        bool moreB = (u < NT2 - 1);
        const unsigned short* Ac = As[sr];
        const unsigned short* Bc = Bs[u & 1];

        // stages first: B(u+1)x3 then A(u+2)x4 (vmcnt retire-order)
        if (prod && moreB) { stageB(sbw, 0, u + 1); stageB(sbw, 1, u + 1);
                             stageB(sbw, 2, u + 1); }
        if (prod && moreA) { stageA(sw, 0, u + 2); stageA(sw, 1, u + 2);
                             stageA(sw, 2, u + 2); stageA(sw, 3, u + 2); }

        // all fragment reads (14 b128)
        #pragma unroll
        for (int nt = 0; nt < 3; ++nt)
            #pragma unroll
            for (int kk = 0; kk < 2; ++kk)
                fb[nt][kk] = *(const short8*)&Bc[(wn + nt * 16 + lm) * BK2 +
                                                 ((((kk << 2) | quad) ^ e) * 8)];
        #pragma unroll
        for (int mt = 0; mt < 4; ++mt)
            #pragma unroll
            for (int kk = 0; kk < 2; ++kk)
                fa[mt][kk] = *(const short8*)&Ac[(wm + mt * 16 + lm) * BK2 +
                                                 ((((kk << 2) | quad) ^ e) * 8)];

        __builtin_amdgcn_s_setprio(1);
        #pragma unroll
        for (int mt = 0; mt < 4; ++mt)
            #pragma unroll
            for (int nt = 0; nt < 3; ++nt)
                #pragma unroll
                for (int kk = 0; kk < 2; ++kk)
                    acc[mt][nt] = __builtin_amdgcn_mfma_f32_16x16x32_bf16(
                        fa[mt][kk], fb[nt][kk], acc[mt][nt], 0, 0, 0);
        __builtin_amdgcn_s_setprio(0);

        // boundary: retire A(u+1)x4 + B(u+1)x3, keep A(u+2)x4 in flight
        if (moreA)      asm volatile("s_waitcnt vmcnt(4)" ::: "memory");
        else if (moreB) asm volatile("s_waitcnt vmcnt(0)" ::: "memory");
        __builtin_amdgcn_s_barrier();

        sr = sr + 1 == 3 ? 0 : sr + 1;
    }

    // epilogue: per-wave 64x48 region
    if (isf) {
        float* C = (float*)outp + (size_t)ib * NN * FOUT;
        #pragma unroll
        for (int nt = 0; nt < 3; ++nt) {
            int o = o0 + wn + nt * 16 + lm;
            float bv = bf[o];
            #pragma unroll
            for (int mt = 0; mt < 4; ++mt) {
                int i = i0 + wm + mt * 16 + quad * 4;
                #pragma unroll
                for (int r = 0; r < 4; ++r)
                    C[(size_t)(i + r) * FOUT + o] = acc[mt][nt][r] + bv;
            }
        }
    } else {
        unsigned short* C = (unsigned short*)outp + (size_t)ib * NN * FOUT;
        #pragma unroll
        for (int nt = 0; nt < 3; ++nt) {
            int o = o0 + wn + nt * 16 + lm;
            float bv = bf[o];
            #pragma unroll
            for (int mt = 0; mt < 4; ++mt) {
                int i = i0 + wm + mt * 16 + quad * 4;
                #pragma unroll
                for (int r = 0; r < 4; ++r)
                    C[(size_t)(i + r) * FOUT + o] = f2bits(acc[mt][nt][r] + bv);
            }
        }
    }
}

// ---------------------------------------------------------------------------
extern "C" void kernel_launch(void* const* d_in, const int* in_sizes, int n_in,
                              void* d_out, int out_size, void* d_ws, size_t ws_size,
                              hipStream_t stream)
{
    const void* h_raw   = d_in[0];
    const void* adj_raw = d_in[1];
    const void* w_raw   = d_in[2];
    const void* as_raw  = d_in[3];
    const void* ad_raw  = d_in[4];
    const void* b_raw   = d_in[5];

    char* ws = (char*)d_ws;
    size_t off = 0;
    unsigned short* hpT = (unsigned short*)(ws + off); off += (size_t)BS * NH * FOUT * NN * 2;
    float* asr = (float*)(ws + off);            off += (size_t)BS * NH * NN * 4;
    float* ads = (float*)(ws + off);            off += (size_t)BS * NH * NN * 4;
    // union: {h_bf16, wt_bf16} live only until k_gemm_hw; P overlays after.
    size_t uoff = off;
    unsigned short* P    = (unsigned short*)(ws + uoff);
    unsigned short* h_bf = (unsigned short*)(ws + uoff); uoff += (size_t)BS * NN * FIN * 2;
    unsigned short* wt_b = (unsigned short*)(ws + uoff); uoff += (size_t)NH * FOUT * FIN * 2;
    off += (size_t)BS * NH * NN * NN * 2;       // P dominates the union
    float* asf = (float*)(ws + off);            off += (size_t)NH * FOUT * 4;
    float* adf = (float*)(ws + off);            off += (size_t)NH * FOUT * 4;
    float* bff = (float*)(ws + off);            off += 4096;

    k_prep<<<NB_H + NB_W + NB_Z + 1, 256, 0, stream>>>(
        h_raw, h_bf, w_raw, wt_b, as_raw, ad_raw, b_raw, asf, adf, bff, asr);
    k_gemm_hw<<<dim3(HGRID), 512, 0, stream>>>(
        h_bf, wt_b, hpT, asf, adf, asr, ads);
    k_softmax_p<<<dim3(BS * NN), 256, 0, stream>>>(asr, ads, adj_raw, P);
    k_gemm_out<<<dim3(GRID2), 1024, 0, stream>>>(
        P, hpT, bff, d_out, (const unsigned short*)h_raw);
}